// Round 5
// baseline (201.384 us; speedup 1.0000x reference)
//
#include <hip/hip_runtime.h>
#include <hip/hip_bf16.h>

#define NROWS 4096
#define DDIM  256
#define EPS   1e-8f
// Normalized rows are scaled by sqrt(2*log2(e)) so the MFMA dot product IS the
// exp2 argument: exp2(<se_i, se_j>) = exp(<e_i,e_j>/T), T = 0.5.
#define SCALE 1.69864944f
#define LN2   0.69314718056f

#define NJ 64          // j-slices (grid.y)
#define JS 128         // cols per slice (8 column-groups of 16)
#define NCG (JS / 16)  // 8 cgs per slice == 8 waves per block
// LDS fragment-ordered: [cg(8)][ks(8)][lane(64)][8 shorts] = 64 KB (1 buffer)
#define LDSSH (8 * 8 * 64 * 8)

typedef __attribute__((ext_vector_type(8))) short short8;
typedef __attribute__((ext_vector_type(4))) float f32x4;

#if __has_builtin(__builtin_amdgcn_exp2f)
#define EXP2F(x) __builtin_amdgcn_exp2f(x)
#else
#define EXP2F(x) exp2f(x)
#endif

__device__ __forceinline__ unsigned short f2bf(float x) {
    union { __hip_bfloat16 h; unsigned short u; } c;
    c.h = __float2bfloat16(x);
    return c.u;
}

__device__ __forceinline__ float bf2f(unsigned short u) {
    union { float f; unsigned int i; } c;
    c.i = ((unsigned int)u) << 16;
    return c.f;
}

// ---------------------------------------------------------------------------
// Kernel 1 (fused normalize + positive_sim): one wave owns the PAIR (i, N+i).
// Loads both rows once, L2-normalizes both -> scaled bf16, computes
// positive_sim from the bf16-rounded values, zeroes S.
// grid = N/4 blocks x 256 threads.
__global__ void prep_kernel(const float* __restrict__ a,
                            const float* __restrict__ b,
                            unsigned short* __restrict__ en,
                            float* __restrict__ S,
                            float* __restrict__ pos, int N) {
    const int wave = threadIdx.x >> 6, lane = threadIdx.x & 63;
    const int row = blockIdx.x * 4 + wave;          // pair index in [0,N)
    const float4 va = reinterpret_cast<const float4*>(a + (size_t)row * DDIM)[lane];
    const float4 vb = reinterpret_cast<const float4*>(b + (size_t)row * DDIM)[lane];
    float ssa = va.x * va.x + va.y * va.y + va.z * va.z + va.w * va.w;
    float ssb = vb.x * vb.x + vb.y * vb.y + vb.z * vb.z + vb.w * vb.w;
    #pragma unroll
    for (int off = 32; off > 0; off >>= 1) {
        ssa += __shfl_xor(ssa, off);
        ssb += __shfl_xor(ssb, off);
    }
    const float inva = SCALE / fmaxf(sqrtf(ssa), EPS * SCALE);
    const float invb = SCALE / fmaxf(sqrtf(ssb), EPS * SCALE);
    ushort4 oa, ob;
    oa.x = f2bf(va.x * inva); oa.y = f2bf(va.y * inva);
    oa.z = f2bf(va.z * inva); oa.w = f2bf(va.w * inva);
    ob.x = f2bf(vb.x * invb); ob.y = f2bf(vb.y * invb);
    ob.z = f2bf(vb.z * invb); ob.w = f2bf(vb.w * invb);
    *reinterpret_cast<ushort4*>(en + (size_t)row * DDIM + lane * 4) = oa;
    *reinterpret_cast<ushort4*>(en + (size_t)(N + row) * DDIM + lane * 4) = ob;
    float d = bf2f(oa.x) * bf2f(ob.x) + bf2f(oa.y) * bf2f(ob.y) +
              bf2f(oa.z) * bf2f(ob.z) + bf2f(oa.w) * bf2f(ob.w);
    #pragma unroll
    for (int off = 32; off > 0; off >>= 1) d += __shfl_xor(d, off);
    if (lane == 0) {
        pos[row] = d * LN2;
        S[row] = 0.0f;
    }
}

// ---------------------------------------------------------------------------
// Kernel 2: masked exp row-sums via MFMA. Occupancy-first structure:
// 512-thread blocks (8 waves x 64 A-rows), JS=128 B-cols staged ONCE into a
// single 64 KB LDS buffer (wave w stages cg w via 8 global_load_lds). One
// vmcnt(0) + one s_barrier, then the whole compute phase (8 cg x
// {8 ds_read_b128 + 32 MFMA + branch-free exp epilogue}) has ZERO barriers —
// 2 blocks/CU x 8 waves = 4 waves/SIMD freely overlap MFMA/trans/LDS pipes.
// grid = (4096/512 = 8 i-blocks, NJ=64 j-slices) = 512 blocks = 2/CU.
// MFMA 16x16x32 bf16 verified layouts:
//   A/B operand: elem j of lane l = M[base + (l&15)][ks*32 + (l>>4)*8 + j]
//   C/D:         reg r of lane l  = C[(l>>4)*4 + r][l&15]
__global__ __launch_bounds__(512, 4) void simsum_kernel(
        const short* __restrict__ en,
        float* __restrict__ S) {
    __shared__ short bt[LDSSH];
    const int tid = threadIdx.x;
    const int wave = tid >> 6, lane = tid & 63;
    const int lrow = lane & 15, quad = lane >> 4;
    const int i0 = blockIdx.x * 512 + wave * 64;
    const int jb = blockIdx.y * JS;

    // Stage this wave's cg (16 cols x K=256 = 8 KB) via async DMA. LDS dest is
    // wave-uniform base + lane*16B == fragment order for the ds_read below.
    {
        const short* g = en + (size_t)(jb + wave * 16 + lrow) * DDIM + quad * 8;
        short* l = bt + wave * 4096;
        #pragma unroll
        for (int ks = 0; ks < 8; ++ks) {
            __builtin_amdgcn_global_load_lds(
                (const __attribute__((address_space(1))) void*)(g + ks * 32),
                (__attribute__((address_space(3))) void*)(l + ks * 512),
                16, 0, 0);
        }
    }

    // A fragments: 4 row-tiles x K=256, loaded once (concurrent with DMA).
    short8 afrag[4][8];
    #pragma unroll
    for (int t = 0; t < 4; ++t)
        #pragma unroll
        for (int ks = 0; ks < 8; ++ks)
            afrag[t][ks] = *reinterpret_cast<const short8*>(
                en + (size_t)(i0 + t * 16 + lrow) * DDIM + ks * 32 + quad * 8);

    float rowsum[4][4];
    #pragma unroll
    for (int t = 0; t < 4; ++t)
        #pragma unroll
        for (int r = 0; r < 4; ++r) rowsum[t][r] = 0.0f;

    // Single sync point of the whole kernel: all DMA landed, all waves ready.
    asm volatile("s_waitcnt vmcnt(0)" ::: "memory");
    __builtin_amdgcn_s_barrier();

    // Barrier-free compute: 8 tiles of 64x16.
    #pragma unroll
    for (int cg = 0; cg < NCG; ++cg) {
        f32x4 acc[4];
        #pragma unroll
        for (int t = 0; t < 4; ++t) acc[t] = f32x4{0.f, 0.f, 0.f, 0.f};
        #pragma unroll
        for (int ks = 0; ks < 8; ++ks) {
            const short8 bfrag = *reinterpret_cast<const short8*>(
                bt + cg * 4096 + ks * 512 + lane * 8);
            #pragma unroll
            for (int t = 0; t < 4; ++t)
                acc[t] = __builtin_amdgcn_mfma_f32_16x16x32_bf16(
                    afrag[t][ks], bfrag, acc[t], 0, 0, 0);
        }
        // Branch-free epilogue: exclude the (at most one) diagonal-family
        // element per lane via compare+select (j%N == i%N).
        const int cm = (jb + cg * 16 + lrow) & (NROWS - 1);
        #pragma unroll
        for (int t = 0; t < 4; ++t) {
            const int dd = cm - (i0 + t * 16 + quad * 4);  // match when dd==r
            #pragma unroll
            for (int r = 0; r < 4; ++r) {
                const float ed = EXP2F(acc[t][r]);
                rowsum[t][r] += (dd == r) ? 0.0f : ed;
            }
        }
    }

    // Reduce each rowsum over the 16 lanes sharing a quad, then one atomic.
    #pragma unroll
    for (int t = 0; t < 4; ++t) {
        #pragma unroll
        for (int r = 0; r < 4; ++r) {
            float v = rowsum[t][r];
            v += __shfl_xor(v, 1);
            v += __shfl_xor(v, 2);
            v += __shfl_xor(v, 4);
            v += __shfl_xor(v, 8);
            rowsum[t][r] = v;
        }
        if (lrow < 4) {
            const float v = (lrow == 0) ? rowsum[t][0]
                          : (lrow == 1) ? rowsum[t][1]
                          : (lrow == 2) ? rowsum[t][2]
                          :               rowsum[t][3];
            atomicAdd(&S[i0 + t * 16 + quad * 4 + lrow], v);
        }
    }
}

// ---------------------------------------------------------------------------
// Kernel 3: loss = -(1/N) * sum_i (pos[i] - log(S[i])). One block x 1024.
__global__ void loss_kernel(const float* __restrict__ S,
                            const float* __restrict__ pos,
                            float* __restrict__ out, int N) {
    const int i = threadIdx.x * 4;
    float acc = 0.0f;
    if (i < N) {
        const float4 s4 = *reinterpret_cast<const float4*>(S + i);
        const float4 p4 = *reinterpret_cast<const float4*>(pos + i);
        acc = (p4.x - __logf(s4.x)) + (p4.y - __logf(s4.y)) +
              (p4.z - __logf(s4.z)) + (p4.w - __logf(s4.w));
    }
    #pragma unroll
    for (int off = 32; off > 0; off >>= 1) acc += __shfl_xor(acc, off);
    __shared__ float wsum[16];
    const int wave = threadIdx.x >> 6, lane = threadIdx.x & 63;
    if (lane == 0) wsum[wave] = acc;
    __syncthreads();
    if (threadIdx.x == 0) {
        float tot = 0.0f;
        #pragma unroll
        for (int w = 0; w < 16; ++w) tot += wsum[w];
        out[0] = -tot / (float)N;
    }
}

// ---------------------------------------------------------------------------
extern "C" void kernel_launch(void* const* d_in, const int* in_sizes, int n_in,
                              void* d_out, int out_size, void* d_ws, size_t ws_size,
                              hipStream_t stream) {
    const float* a = (const float*)d_in[0];
    const float* b = (const float*)d_in[1];
    float* out = (float*)d_out;
    const int N = NROWS;

    char* ws = (char*)d_ws;
    unsigned short* en = (unsigned short*)ws;                  // 2N*D*2 = 4 MB
    float* S = (float*)(ws + (size_t)2 * N * DDIM * sizeof(unsigned short));
    float* pos = S + N;

    prep_kernel<<<N / 4, 256, 0, stream>>>(a, b, en, S, pos, N);
    simsum_kernel<<<dim3(NROWS / 512, NJ), 512, 0, stream>>>((const short*)en, S);
    loss_kernel<<<1, 1024, 0, stream>>>(S, pos, out, N);
}

// Round 6
// 90.874 us; speedup vs baseline: 2.2161x; 2.2161x over previous
//
#include <hip/hip_runtime.h>
#include <hip/hip_bf16.h>

#define NROWS 4096
#define DDIM  256
#define EPS   1e-8f
// Normalized rows are scaled by sqrt(2*log2(e)) so the MFMA dot product IS the
// exp2 argument: exp2(<se_i, se_j>) = exp(<e_i,e_j>/T), T = 0.5.
#define SCALE 1.69864944f
#define LN2   0.69314718056f

#define NJ 32          // j-slices (grid.y)
#define JS 256         // cols per slice
#define BT 64          // cols per staged LDS chunk
#define CH (JS / BT)   // 4 chunks per slice
// LDS fragment-ordered: [buf][cgrp(4)][ks(8)][lane(64)][8 shorts] = 32 KB/buf
#define BUFSH (4 * 8 * 64 * 8)

typedef __attribute__((ext_vector_type(8))) short short8;
typedef __attribute__((ext_vector_type(4))) float f32x4;

#if __has_builtin(__builtin_amdgcn_exp2f)
#define EXP2F(x) __builtin_amdgcn_exp2f(x)
#else
#define EXP2F(x) exp2f(x)
#endif

__device__ __forceinline__ unsigned short f2bf(float x) {
    union { __hip_bfloat16 h; unsigned short u; } c;
    c.h = __float2bfloat16(x);
    return c.u;
}

__device__ __forceinline__ float bf2f(unsigned short u) {
    union { float f; unsigned int i; } c;
    c.i = ((unsigned int)u) << 16;
    return c.f;
}

// ---------------------------------------------------------------------------
// Kernel 1 (fused normalize + positive_sim): one wave owns the PAIR (i, N+i).
// grid = N/4 blocks x 256 threads.
__global__ void prep_kernel(const float* __restrict__ a,
                            const float* __restrict__ b,
                            unsigned short* __restrict__ en,
                            float* __restrict__ S,
                            float* __restrict__ pos, int N) {
    const int wave = threadIdx.x >> 6, lane = threadIdx.x & 63;
    const int row = blockIdx.x * 4 + wave;          // pair index in [0,N)
    const float4 va = reinterpret_cast<const float4*>(a + (size_t)row * DDIM)[lane];
    const float4 vb = reinterpret_cast<const float4*>(b + (size_t)row * DDIM)[lane];
    float ssa = va.x * va.x + va.y * va.y + va.z * va.z + va.w * va.w;
    float ssb = vb.x * vb.x + vb.y * vb.y + vb.z * vb.z + vb.w * vb.w;
    #pragma unroll
    for (int off = 32; off > 0; off >>= 1) {
        ssa += __shfl_xor(ssa, off);
        ssb += __shfl_xor(ssb, off);
    }
    const float inva = SCALE / fmaxf(sqrtf(ssa), EPS * SCALE);
    const float invb = SCALE / fmaxf(sqrtf(ssb), EPS * SCALE);
    ushort4 oa, ob;
    oa.x = f2bf(va.x * inva); oa.y = f2bf(va.y * inva);
    oa.z = f2bf(va.z * inva); oa.w = f2bf(va.w * inva);
    ob.x = f2bf(vb.x * invb); ob.y = f2bf(vb.y * invb);
    ob.z = f2bf(vb.z * invb); ob.w = f2bf(vb.w * invb);
    *reinterpret_cast<ushort4*>(en + (size_t)row * DDIM + lane * 4) = oa;
    *reinterpret_cast<ushort4*>(en + (size_t)(N + row) * DDIM + lane * 4) = ob;
    float d = bf2f(oa.x) * bf2f(ob.x) + bf2f(oa.y) * bf2f(ob.y) +
              bf2f(oa.z) * bf2f(ob.z) + bf2f(oa.w) * bf2f(ob.w);
    #pragma unroll
    for (int off = 32; off > 0; off >>= 1) d += __shfl_xor(d, off);
    if (lane == 0) {
        pos[row] = d * LN2;
        S[row] = 0.0f;
    }
}

// ---------------------------------------------------------------------------
// Kernel 2: masked exp row-sums via MFMA — occupancy-corrected structure.
// 512-thread blocks (8 waves), each wave owns 32 A-rows (t=2: afrag = 64
// VGPRs, total live state ~110 <= the 128-reg cap from __launch_bounds__
// (512,2)) so 2 blocks/CU x 8 waves = 4 waves/SIMD — 2x the R3 residency
// that profiling showed was the binding constraint (Occ 17%, both pipes
// ~10%, conflicts 0). B staged in double-buffered 32KB LDS chunks via
// global_load_lds (fragment order); 8 waves share staging (4 DMA each).
// R2's race-verified counted-vmcnt chunk schedule retained (vmcnt(4)).
// grid = (4096/256 = 16 i-blocks, NJ=32 j-slices) = 512 blocks = 2/CU.
// MFMA 16x16x32 bf16 verified layouts:
//   A/B operand: elem j of lane l = M[base + (l&15)][ks*32 + (l>>4)*8 + j]
//   C/D:         reg r of lane l  = C[(l>>4)*4 + r][l&15]
__global__ __launch_bounds__(512, 2) void simsum_kernel(
        const short* __restrict__ en,
        float* __restrict__ S) {
    __shared__ short bt[2 * BUFSH];
    const int tid = threadIdx.x;
    const int wave = tid >> 6, lane = tid & 63;
    const int lrow = lane & 15, quad = lane >> 4;
    const int i0 = blockIdx.x * 256 + wave * 32;
    const int jb = blockIdx.y * JS;

    // A fragments: 2 row-tiles x K=256, loaded once (64 VGPRs).
    short8 afrag[2][8];
    #pragma unroll
    for (int t = 0; t < 2; ++t)
        #pragma unroll
        for (int ks = 0; ks < 8; ++ks)
            afrag[t][ks] = *reinterpret_cast<const short8*>(
                en + (size_t)(i0 + t * 16 + lrow) * DDIM + ks * 32 + quad * 8);

    float rowsum[2][4];
    #pragma unroll
    for (int t = 0; t < 2; ++t)
        #pragma unroll
        for (int r = 0; r < 4; ++r) rowsum[t][r] = 0.0f;

    // Async stage of one 64-col chunk, split across 8 waves: wave w covers
    // cg = w>>1 (16 cols) and k-half (w&1)*4..+4 — 4 global_load_lds each.
    // LDS dest is wave-uniform base + lane*16B == fragment order.
    const int scg = wave >> 1, skh = (wave & 1) * 4;
    auto stage = [&](int jc, int buf) {
        const short* g = en + (size_t)(jc + scg * 16 + lrow) * DDIM
                         + skh * 32 + quad * 8;
        short* l = bt + buf * BUFSH + scg * 4096 + skh * 512;
        #pragma unroll
        for (int ks = 0; ks < 4; ++ks) {
            __builtin_amdgcn_global_load_lds(
                (const __attribute__((address_space(1))) void*)(g + ks * 32),
                (__attribute__((address_space(3))) void*)(l + ks * 512),
                16, 0, 0);
        }
    };

    stage(jb, 0);
    for (int c = 0; c < CH; ++c) {
        // Barrier A: all waves' ds_reads of the buffer stage(c+1) will
        // overwrite have been DELIVERED (lgkmcnt(0)) and consumed.
        asm volatile("s_waitcnt lgkmcnt(0)" ::: "memory");
        __builtin_amdgcn_s_barrier();
        if (c + 1 < CH) {
            stage(jb + (c + 1) * BT, (c + 1) & 1);
            asm volatile("s_waitcnt vmcnt(4)" ::: "memory");  // chunk c landed
        } else {
            asm volatile("s_waitcnt vmcnt(0)" ::: "memory");  // final chunk
        }
        __builtin_amdgcn_sched_barrier(0);
        __builtin_amdgcn_s_barrier();    // Barrier B: chunk c visible to all
        const short* lb = bt + (c & 1) * BUFSH;
        #pragma unroll
        for (int cg = 0; cg < 4; ++cg) {
            f32x4 acc[2];
            #pragma unroll
            for (int t = 0; t < 2; ++t) acc[t] = f32x4{0.f, 0.f, 0.f, 0.f};
            __builtin_amdgcn_s_setprio(1);
            #pragma unroll
            for (int ks = 0; ks < 8; ++ks) {
                const short8 bfrag = *reinterpret_cast<const short8*>(
                    lb + cg * 4096 + ks * 512 + lane * 8);
                #pragma unroll
                for (int t = 0; t < 2; ++t)
                    acc[t] = __builtin_amdgcn_mfma_f32_16x16x32_bf16(
                        afrag[t][ks], bfrag, acc[t], 0, 0, 0);
            }
            __builtin_amdgcn_s_setprio(0);
            // Branch-free epilogue: exclude the (at most one) diagonal-family
            // element per lane via compare+select (j%N == i%N).
            const int cm = (jb + c * BT + cg * 16 + lrow) & (NROWS - 1);
            #pragma unroll
            for (int t = 0; t < 2; ++t) {
                const int dd = cm - (i0 + t * 16 + quad * 4);  // match: dd==r
                #pragma unroll
                for (int r = 0; r < 4; ++r) {
                    const float ed = EXP2F(acc[t][r]);
                    rowsum[t][r] += (dd == r) ? 0.0f : ed;
                }
            }
        }
    }

    // Reduce each rowsum over the 16 lanes sharing a quad, then one atomic.
    #pragma unroll
    for (int t = 0; t < 2; ++t) {
        #pragma unroll
        for (int r = 0; r < 4; ++r) {
            float v = rowsum[t][r];
            v += __shfl_xor(v, 1);
            v += __shfl_xor(v, 2);
            v += __shfl_xor(v, 4);
            v += __shfl_xor(v, 8);
            rowsum[t][r] = v;
        }
        if (lrow < 4) {
            const float v = (lrow == 0) ? rowsum[t][0]
                          : (lrow == 1) ? rowsum[t][1]
                          : (lrow == 2) ? rowsum[t][2]
                          :               rowsum[t][3];
            atomicAdd(&S[i0 + t * 16 + quad * 4 + lrow], v);
        }
    }
}

// ---------------------------------------------------------------------------
// Kernel 3: loss = -(1/N) * sum_i (pos[i] - log(S[i])). One block x 1024.
__global__ void loss_kernel(const float* __restrict__ S,
                            const float* __restrict__ pos,
                            float* __restrict__ out, int N) {
    const int i = threadIdx.x * 4;
    float acc = 0.0f;
    if (i < N) {
        const float4 s4 = *reinterpret_cast<const float4*>(S + i);
        const float4 p4 = *reinterpret_cast<const float4*>(pos + i);
        acc = (p4.x - __logf(s4.x)) + (p4.y - __logf(s4.y)) +
              (p4.z - __logf(s4.z)) + (p4.w - __logf(s4.w));
    }
    #pragma unroll
    for (int off = 32; off > 0; off >>= 1) acc += __shfl_xor(acc, off);
    __shared__ float wsum[16];
    const int wave = threadIdx.x >> 6, lane = threadIdx.x & 63;
    if (lane == 0) wsum[wave] = acc;
    __syncthreads();
    if (threadIdx.x == 0) {
        float tot = 0.0f;
        #pragma unroll
        for (int w = 0; w < 16; ++w) tot += wsum[w];
        out[0] = -tot / (float)N;
    }
}

// ---------------------------------------------------------------------------
extern "C" void kernel_launch(void* const* d_in, const int* in_sizes, int n_in,
                              void* d_out, int out_size, void* d_ws, size_t ws_size,
                              hipStream_t stream) {
    const float* a = (const float*)d_in[0];
    const float* b = (const float*)d_in[1];
    float* out = (float*)d_out;
    const int N = NROWS;

    char* ws = (char*)d_ws;
    unsigned short* en = (unsigned short*)ws;                  // 2N*D*2 = 4 MB
    float* S = (float*)(ws + (size_t)2 * N * DDIM * sizeof(unsigned short));
    float* pos = S + N;

    prep_kernel<<<N / 4, 256, 0, stream>>>(a, b, en, S, pos, N);
    simsum_kernel<<<dim3(NROWS / 256, NJ), 512, 0, stream>>>((const short*)en, S);
    loss_kernel<<<1, 1024, 0, stream>>>(S, pos, out, N);
}